// Round 5
// baseline (7286.185 us; speedup 1.0000x reference)
//
#include <hip/hip_runtime.h>
#include <stdint.h>

#define BB 256
#define SS 64
#define TT 20
#define HH 1024
#define EE 100
#define G3 3072
#define G4 4096
#define KE 1152     // 1024 + 128 (E padded to 128)
#define VV 32000

typedef unsigned short ushort_t;
typedef short bf16x8 __attribute__((ext_vector_type(8)));
typedef float f32x4 __attribute__((ext_vector_type(4)));

#define DEV static __device__ __forceinline__

DEV float bf2f(ushort_t h) {
    union { uint32_t u; float f; } c; c.u = ((uint32_t)h) << 16; return c.f;
}
DEV ushort_t f2bf(float x) {
    union { float f; uint32_t u; } c; c.f = x;
    uint32_t r = (c.u + 0x7fffu + ((c.u >> 16) & 1u)) >> 16;
    return (ushort_t)r;
}
DEV float sigm(float x) { return 1.f / (1.f + expf(-x)); }

#define MFMA16(a, b, c) __builtin_amdgcn_mfma_f32_16x16x32_bf16(a, b, c, 0, 0, 0)

// Device-scope grid barrier: monotonic generation, zeroed by prep_x each launch.
DEV void gridbar(int* cnt, int* gen, int target, int nblk) {
    __syncthreads();
    if (threadIdx.x == 0) {
        __threadfence();
        int tkt = __hip_atomic_fetch_add(cnt, 1, __ATOMIC_ACQ_REL, __HIP_MEMORY_SCOPE_AGENT);
        if (tkt == nblk - 1) {
            __hip_atomic_store(cnt, 0, __ATOMIC_RELAXED, __HIP_MEMORY_SCOPE_AGENT);
            __hip_atomic_fetch_add(gen, 1, __ATOMIC_RELEASE, __HIP_MEMORY_SCOPE_AGENT);
        } else {
            while (__hip_atomic_load(gen, __ATOMIC_ACQUIRE, __HIP_MEMORY_SCOPE_AGENT) < target) {}
        }
        __threadfence();
    }
    __syncthreads();
}

// ---------------------------------------------------------------------------
// prep_w: bf16 W_enc_big [4096][1152], W_dec_pad [3072][1152] from fp32.
// ---------------------------------------------------------------------------
__global__ void prep_w(const float* __restrict__ W_hh_e, const float* __restrict__ W_ih_e,
                       const float* __restrict__ W_ih_d,
                       ushort_t* __restrict__ W_enc_big, ushort_t* __restrict__ W_dec_pad) {
    int idx = blockIdx.x * 256 + threadIdx.x;  // (G4+G3) * (KE/8)
    int n = idx / 144, kc = (idx - n * 144) * 8;
    ushort_t o[8];
    if (n < G4) {
        if (kc < HH) {
            if (n < G3) {
#pragma unroll
                for (int u = 0; u < 8; ++u) o[u] = f2bf(W_hh_e[(size_t)n * HH + kc + u]);
            } else {
#pragma unroll
                for (int u = 0; u < 8; ++u) o[u] = 0;
            }
        } else {
            int kk = kc - HH;
#pragma unroll
            for (int u = 0; u < 8; ++u) {
                int k2 = kk + u;
                ushort_t v = 0;
                if (k2 < EE) {
                    if (n < 2048) v = f2bf(W_ih_e[(size_t)n * EE + k2]);
                    else if (n >= G3) v = f2bf(W_ih_e[(size_t)(n - HH) * EE + k2]);
                }
                o[u] = v;
            }
        }
        *(int4*)(W_enc_big + (size_t)n * KE + kc) = *(int4*)o;
    } else {
        int nd = n - G4;
        if (kc < 128) {
#pragma unroll
            for (int u = 0; u < 8; ++u) {
                int k2 = kc + u;
                o[u] = (k2 < EE) ? f2bf(W_ih_d[(size_t)nd * 1124 + k2]) : (ushort_t)0;
            }
        } else {
#pragma unroll
            for (int u = 0; u < 8; ++u) o[u] = f2bf(W_ih_d[(size_t)nd * 1124 + EE + (kc - 128) + u]);
        }
        *(int4*)(W_dec_pad + (size_t)nd * KE + kc) = *(int4*)o;
    }
}

// fp32 -> bf16 copies of W_hh_d and W_fc
__global__ void conv_w(const float* __restrict__ W_hh_d, const float* __restrict__ W_fc,
                       ushort_t* __restrict__ W_hhd_b, ushort_t* __restrict__ W_fc_b) {
    int idx = blockIdx.x * 256 + threadIdx.x;
    const int N1 = G3 * HH / 8;
    const float* src;
    ushort_t* dst;
    size_t e;
    if (idx < N1) { e = (size_t)idx * 8; src = W_hh_d; dst = W_hhd_b; }
    else { e = (size_t)(idx - N1) * 8; src = W_fc; dst = W_fc_b; }
    float4 a = *(const float4*)(src + e);
    float4 b = *(const float4*)(src + e + 4);
    ushort_t o[8] = {f2bf(a.x), f2bf(a.y), f2bf(a.z), f2bf(a.w),
                     f2bf(b.x), f2bf(b.y), f2bf(b.z), f2bf(b.w)};
    *(int4*)(dst + e) = *(int4*)o;
}

// ---------------------------------------------------------------------------
// prep_x: emb_pad, A_enc0 = [h0 | emb_0], A_dec demb part, zero sum_exp + bars
// ---------------------------------------------------------------------------
__global__ void prep_x(const int* __restrict__ inputs, const int* __restrict__ targets,
                       const float* __restrict__ h0, const float* __restrict__ E_enc,
                       const float* __restrict__ E_dec,
                       ushort_t* __restrict__ emb_pad, ushort_t* __restrict__ A_enc,
                       ushort_t* __restrict__ A_dec, float* __restrict__ sum_exp,
                       int* __restrict__ bars) {
    int idx = blockIdx.x * 256 + threadIdx.x;
    const int R0 = SS * BB * 128;
    const int R1 = R0 + BB * KE;
    const int R2 = R1 + (TT - 1) * BB * 128;
    const int R3 = R2 + (TT - 1) * BB;
    const int R4 = R3 + 8;
    if (idx < R0) {
        int s = idx >> 15;
        int r = idx & 32767;
        int b = r >> 7, k = r & 127;
        emb_pad[idx] = (k < EE) ? f2bf(E_enc[(size_t)inputs[b * SS + s] * EE + k]) : (ushort_t)0;
    } else if (idx < R1) {
        int i = idx - R0;
        int b = i / KE, c = i - b * KE;
        ushort_t v;
        if (c < HH) v = f2bf(h0[b * HH + c]);
        else { int kk = c - HH; v = (kk < EE) ? f2bf(E_enc[(size_t)inputs[b * SS] * EE + kk]) : (ushort_t)0; }
        A_enc[i] = v;
    } else if (idx < R2) {
        int i = idx - R1;
        int t = i >> 15;
        int r = i & 32767;
        int b = r >> 7, k = r & 127;
        int tok = (t == 0) ? 1 : targets[b * TT + t];
        A_dec[((size_t)(t * BB + b)) * KE + k] = (k < EE) ? f2bf(E_dec[(size_t)tok * EE + k]) : (ushort_t)0;
    } else if (idx < R3) {
        sum_exp[idx - R2] = 0.f;
    } else if (idx < R4) {
        bars[idx - R3] = 0;
    }
}

// ---------------------------------------------------------------------------
// Persistent encoder: 128 blocks (32 j x 4 m), 64 steps with one grid barrier
// each. h and context live in registers for the whole sequence.
// Block = 64 batch rows x 32 hidden cols x 4 gate groups (one wave each).
// ---------------------------------------------------------------------------
__global__ __launch_bounds__(256) void enc_all(
    ushort_t* __restrict__ A0, ushort_t* __restrict__ A1,
    const ushort_t* __restrict__ W, const float* __restrict__ bi,
    const float* __restrict__ bh, const float* __restrict__ h0,
    const ushort_t* __restrict__ emb_pad, const int* __restrict__ lengths,
    float* __restrict__ ctx_f, ushort_t* __restrict__ ctx_b,
    int* __restrict__ cnt, int* __restrict__ gen) {
    __shared__ ushort_t As[64 * 64];
    __shared__ float gbuf[4][64 * 33];
    int tid = threadIdx.x;
    int lane = tid & 63, g = tid >> 6;
    int j0 = blockIdx.x << 5, m0 = blockIdx.y << 6;
    int r16 = lane & 15, q = lane >> 4, q8 = q << 3;
    int srow = tid >> 3, skc = (tid & 7) << 3;
    const int s0 = srow * 64 + skc, s1 = s0 + 32 * 64;
    const ushort_t* wb0 = W + (size_t)(g * 1024 + j0 + r16) * KE + q8;
    const ushort_t* wb1 = wb0 + (size_t)16 * KE;
    // persistent per-thread state (epilogue mapping)
    int m = tid & 63, jc0 = (tid >> 6) << 3;
    int bgl = m0 + m, gj = j0 + jc0;
    int len1 = lengths[bgl] - 1;
    float hreg[8], creg[8];
#pragma unroll
    for (int u = 0; u < 8; ++u) { hreg[u] = h0[(size_t)bgl * HH + gj + u]; creg[u] = 0.f; }
    f32x4 zero = {0.f, 0.f, 0.f, 0.f};

    for (int s = 0; s < SS; ++s) {
        const ushort_t* Ain = (s & 1) ? A1 : A0;
        ushort_t* Aout = (s & 1) ? A0 : A1;
        const ushort_t* ap0 = Ain + (size_t)(m0 + srow) * KE + skc;
        const ushort_t* ap1 = ap0 + (size_t)32 * KE;
        f32x4 acc[4][2];
#pragma unroll
        for (int i = 0; i < 4; ++i) { acc[i][0] = zero; acc[i][1] = zero; }
        bf16x8 wf00 = *(const bf16x8*)(wb0);
        bf16x8 wf01 = *(const bf16x8*)(wb1);
        bf16x8 wf10 = *(const bf16x8*)(wb0 + 32);
        bf16x8 wf11 = *(const bf16x8*)(wb1 + 32);
        for (int k0 = 0; k0 < KE; k0 += 64) {
            int4 va0 = *(const int4*)(ap0 + k0);
            int4 va1 = *(const int4*)(ap1 + k0);
            __syncthreads();
            *(int4*)(As + s0) = va0;
            *(int4*)(As + s1) = va1;
            int kn = (k0 + 64 < KE) ? k0 + 64 : 0;
            bf16x8 wn00 = *(const bf16x8*)(wb0 + kn);
            bf16x8 wn01 = *(const bf16x8*)(wb1 + kn);
            bf16x8 wn10 = *(const bf16x8*)(wb0 + kn + 32);
            bf16x8 wn11 = *(const bf16x8*)(wb1 + kn + 32);
            __syncthreads();
#pragma unroll
            for (int i = 0; i < 4; ++i) {
                bf16x8 af0 = *(const bf16x8*)(As + ((i * 16 + r16) << 6) + q8);
                bf16x8 af1 = *(const bf16x8*)(As + ((i * 16 + r16) << 6) + 32 + q8);
                acc[i][0] = MFMA16(af0, wf00, acc[i][0]);
                acc[i][1] = MFMA16(af0, wf01, acc[i][1]);
                acc[i][0] = MFMA16(af1, wf10, acc[i][0]);
                acc[i][1] = MFMA16(af1, wf11, acc[i][1]);
            }
            wf00 = wn00; wf01 = wn01; wf10 = wn10; wf11 = wn11;
        }
#pragma unroll
        for (int i = 0; i < 4; ++i)
#pragma unroll
            for (int j2 = 0; j2 < 2; ++j2)
#pragma unroll
                for (int r = 0; r < 4; ++r)
                    gbuf[g][(i * 16 + q * 4 + r) * 33 + j2 * 16 + r16] = acc[i][j2][r];
        __syncthreads();
        // cell epilogue (register h)
        const float* g0 = &gbuf[0][m * 33 + jc0];
        const float* g1 = &gbuf[1][m * 33 + jc0];
        const float* g2 = &gbuf[2][m * 33 + jc0];
        const float* g3 = &gbuf[3][m * 33 + jc0];
        ushort_t hb8[8];
        int sel = (len1 == s);
#pragma unroll
        for (int u = 0; u < 8; ++u) {
            int jg = gj + u;
            float rr = sigm(g0[u] + bi[jg] + bh[jg]);
            float zz = sigm(g1[u] + bi[1024 + jg] + bh[1024 + jg]);
            float hn = g2[u] + bh[2048 + jg];
            float inn = g3[u] + bi[2048 + jg];
            float nn = tanhf(inn + rr * hn);
            float h2 = (1.f - zz) * nn + zz * hreg[u];
            hreg[u] = h2;
            hb8[u] = f2bf(h2);
            if (sel) creg[u] = h2;
        }
        *(int4*)(Aout + (size_t)bgl * KE + gj) = *(int4*)hb8;
        if (blockIdx.x == 0 && s + 1 < SS) {
            int rr2 = tid >> 2, c0 = (tid & 3) << 5;
#pragma unroll
            for (int cc = 0; cc < 32; cc += 8) {
                int4 v = *(const int4*)(emb_pad + ((size_t)(s + 1) * BB + m0 + rr2) * 128 + c0 + cc);
                *(int4*)(Aout + (size_t)(m0 + rr2) * KE + 1024 + c0 + cc) = v;
            }
        }
        gridbar(cnt, gen, s + 1, 128);
    }
    // write context
    ushort_t cb8[8];
#pragma unroll
    for (int u = 0; u < 8; ++u) {
        ctx_f[(size_t)bgl * HH + gj + u] = creg[u];
        cb8[u] = f2bf(creg[u]);
    }
    *(int4*)(ctx_b + (size_t)bgl * HH + gj) = *(int4*)cb8;
}

// Fill A_dec ctx columns for all 19 steps; init decoder h (fp32) + hb0 (bf16)
__global__ void fill_ctx(const float* __restrict__ ctx_f, const ushort_t* __restrict__ ctx_b,
                         ushort_t* __restrict__ A_dec, float* __restrict__ h_dec,
                         ushort_t* __restrict__ hb0) {
    int idx = blockIdx.x * 256 + threadIdx.x;  // 19*256*1024
    int t = idx >> 18;
    int r = idx & 262143;
    ushort_t v = ctx_b[r];
    int b = r >> 10;
    int k = r & 1023;
    A_dec[((size_t)(t * BB + b)) * KE + 128 + k] = v;
    if (t == 0) { h_dec[r] = ctx_f[r]; hb0[r] = v; }
}

// ---------------------------------------------------------------------------
// 128x128 LDS-tiled MFMA GEMM (for the one big gi_dec GEMM), bf16 out
// ---------------------------------------------------------------------------
__global__ __launch_bounds__(256) void gemm128(const ushort_t* __restrict__ A,
                                               const ushort_t* __restrict__ W,
                                               ushort_t* __restrict__ C,
                                               int K, int lda, int ldw, int ldc) {
    __shared__ ushort_t As[128 * 32];
    __shared__ ushort_t Bs[128 * 32];
    int tid = threadIdx.x;
    int lane = tid & 63, wave = tid >> 6;
    int m0 = blockIdx.y << 7, n0 = blockIdx.x << 7;
    int row0 = tid >> 2, kc0 = (tid & 3) << 3;
    const ushort_t* a0p = A + (size_t)(m0 + row0) * lda + kc0;
    const ushort_t* a1p = A + (size_t)(m0 + row0 + 64) * lda + kc0;
    const ushort_t* w0p = W + (size_t)(n0 + row0) * ldw + kc0;
    const ushort_t* w1p = W + (size_t)(n0 + row0 + 64) * ldw + kc0;
    int mq = (wave >> 1) << 6, nq = (wave & 1) << 6;
    int r16 = lane & 15, q8 = (lane >> 4) << 3;
    const int lds0 = tid * 8, lds1 = tid * 8 + 2048;
    f32x4 zero4 = {0.f, 0.f, 0.f, 0.f};
    f32x4 acc[4][4];
#pragma unroll
    for (int i = 0; i < 4; ++i)
#pragma unroll
        for (int j = 0; j < 4; ++j) acc[i][j] = zero4;
    for (int k0 = 0; k0 < K; k0 += 32) {
        int4 va0 = *(const int4*)(a0p + k0);
        int4 va1 = *(const int4*)(a1p + k0);
        int4 vb0 = *(const int4*)(w0p + k0);
        int4 vb1 = *(const int4*)(w1p + k0);
        __syncthreads();
        *(int4*)(As + lds0) = va0;
        *(int4*)(As + lds1) = va1;
        *(int4*)(Bs + lds0) = vb0;
        *(int4*)(Bs + lds1) = vb1;
        __syncthreads();
        bf16x8 af[4], bfv[4];
#pragma unroll
        for (int i = 0; i < 4; ++i) af[i] = *(const bf16x8*)(As + ((mq + i * 16 + r16) << 5) + q8);
#pragma unroll
        for (int j = 0; j < 4; ++j) bfv[j] = *(const bf16x8*)(Bs + ((nq + j * 16 + r16) << 5) + q8);
#pragma unroll
        for (int i = 0; i < 4; ++i)
#pragma unroll
            for (int j = 0; j < 4; ++j) acc[i][j] = MFMA16(af[i], bfv[j], acc[i][j]);
    }
    int rbase = (lane >> 4) << 2;
#pragma unroll
    for (int i = 0; i < 4; ++i)
#pragma unroll
        for (int j = 0; j < 4; ++j)
#pragma unroll
            for (int r = 0; r < 4; ++r)
                C[(size_t)(m0 + mq + i * 16 + rbase + r) * ldc + (n0 + nq + j * 16 + r16)] =
                    f2bf(acc[i][j][r]);
}

// ---------------------------------------------------------------------------
// Fused decoder step t: phase 1 (blocks 0..127) recurrent GEMM + GRU cell;
// grid barrier (500 blocks); phase 2 (all blocks) logits 128x128 tile +
// no-max expsum (atomicAdd per row) + target-logit capture.
// ---------------------------------------------------------------------------
__global__ __launch_bounds__(256, 2) void dec_logits(
    const ushort_t* __restrict__ hbin, ushort_t* __restrict__ hbout,
    const ushort_t* __restrict__ Whh, const ushort_t* __restrict__ gi,
    const float* __restrict__ bi, const float* __restrict__ bh,
    float* __restrict__ h,
    const ushort_t* __restrict__ Wf, const float* __restrict__ bfc,
    const int* __restrict__ targets, float* __restrict__ sum_exp,
    float* __restrict__ xtv, int* __restrict__ cnt, int* __restrict__ gen, int t) {
    __shared__ ushort_t As1[64 * 64];
    __shared__ float gbuf[3][64 * 33];
    __shared__ ushort_t As2[128 * 32];
    __shared__ ushort_t Bs2[128 * 32];
    __shared__ float ws2[128][2];
    int tid = threadIdx.x;
    int lane = tid & 63;
    int nb = blockIdx.x;
    // ---- phase 1: recurrent GEMM + cell (blocks 0..127) ----
    if (nb < 128) {
        int g = tid >> 6;
        int j0 = (nb & 31) << 5, m0 = (nb >> 5) << 6;
        int r16 = lane & 15, q = lane >> 4, q8 = q << 3;
        int srow = tid >> 3, skc = (tid & 7) << 3;
        const ushort_t* ap0 = hbin + (size_t)(m0 + srow) * HH + skc;
        const ushort_t* ap1 = ap0 + (size_t)32 * HH;
        const int s0 = srow * 64 + skc, s1 = s0 + 32 * 64;
        const ushort_t* wb0 = Whh + (size_t)(g * 1024 + j0 + r16) * HH + q8;
        const ushort_t* wb1 = wb0 + (size_t)16 * HH;
        f32x4 zero = {0.f, 0.f, 0.f, 0.f};
        f32x4 acc[4][2];
#pragma unroll
        for (int i = 0; i < 4; ++i) { acc[i][0] = zero; acc[i][1] = zero; }
        bf16x8 wf00 = {0,0,0,0,0,0,0,0}, wf01 = wf00, wf10 = wf00, wf11 = wf00;
        if (g < 3) {
            wf00 = *(const bf16x8*)(wb0);
            wf01 = *(const bf16x8*)(wb1);
            wf10 = *(const bf16x8*)(wb0 + 32);
            wf11 = *(const bf16x8*)(wb1 + 32);
        }
        for (int k0 = 0; k0 < HH; k0 += 64) {
            int4 va0 = *(const int4*)(ap0 + k0);
            int4 va1 = *(const int4*)(ap1 + k0);
            __syncthreads();
            *(int4*)(As1 + s0) = va0;
            *(int4*)(As1 + s1) = va1;
            bf16x8 wn00 = wf00, wn01 = wf01, wn10 = wf10, wn11 = wf11;
            if (g < 3) {
                int kn = (k0 + 64 < HH) ? k0 + 64 : 0;
                wn00 = *(const bf16x8*)(wb0 + kn);
                wn01 = *(const bf16x8*)(wb1 + kn);
                wn10 = *(const bf16x8*)(wb0 + kn + 32);
                wn11 = *(const bf16x8*)(wb1 + kn + 32);
            }
            __syncthreads();
            if (g < 3) {
#pragma unroll
                for (int i = 0; i < 4; ++i) {
                    bf16x8 af0 = *(const bf16x8*)(As1 + ((i * 16 + r16) << 6) + q8);
                    bf16x8 af1 = *(const bf16x8*)(As1 + ((i * 16 + r16) << 6) + 32 + q8);
                    acc[i][0] = MFMA16(af0, wf00, acc[i][0]);
                    acc[i][1] = MFMA16(af0, wf01, acc[i][1]);
                    acc[i][0] = MFMA16(af1, wf10, acc[i][0]);
                    acc[i][1] = MFMA16(af1, wf11, acc[i][1]);
                }
            }
            wf00 = wn00; wf01 = wn01; wf10 = wn10; wf11 = wn11;
        }
        if (g < 3) {
#pragma unroll
            for (int i = 0; i < 4; ++i)
#pragma unroll
                for (int j2 = 0; j2 < 2; ++j2)
#pragma unroll
                    for (int r = 0; r < 4; ++r)
                        gbuf[g][(i * 16 + q * 4 + r) * 33 + j2 * 16 + r16] = acc[i][j2][r];
        }
        __syncthreads();
        int m = tid & 63, jc0 = (tid >> 6) << 3;
        int bgl = m0 + m, gj = j0 + jc0;
        const ushort_t* gip = gi + (size_t)bgl * G3;
        ushort_t gr[8], gz[8], gn[8], hb8[8];
        *(int4*)gr = *(const int4*)(gip + gj);
        *(int4*)gz = *(const int4*)(gip + 1024 + gj);
        *(int4*)gn = *(const int4*)(gip + 2048 + gj);
        const float* g0 = &gbuf[0][m * 33 + jc0];
        const float* g1 = &gbuf[1][m * 33 + jc0];
        const float* g2 = &gbuf[2][m * 33 + jc0];
#pragma unroll
        for (int u = 0; u < 8; ++u) {
            int jg = gj + u;
            float rr = sigm(g0[u] + bh[jg] + bf2f(gr[u]) + bi[jg]);
            float zz = sigm(g1[u] + bh[1024 + jg] + bf2f(gz[u]) + bi[1024 + jg]);
            float hn = g2[u] + bh[2048 + jg];
            float inn = bf2f(gn[u]) + bi[2048 + jg];
            float nn = tanhf(inn + rr * hn);
            size_t hi = (size_t)bgl * 1024 + jg;
            float hp = h[hi];
            float h2 = (1.f - zz) * nn + zz * hp;
            h[hi] = h2;
            hb8[u] = f2bf(h2);
        }
        *(int4*)(hbout + (size_t)bgl * 1024 + gj) = *(int4*)hb8;
    }
    gridbar(cnt, gen, t + 1, 500);
    // ---- phase 2: logits tile + CE partials ----
    {
        int wave = tid >> 6;
        int n0 = (nb % 250) << 7, m0 = (nb / 250) << 7;
        int row0 = tid >> 2, kc0 = (tid & 3) << 3;
        const ushort_t* a0p = hbout + (size_t)(m0 + row0) * HH + kc0;
        const ushort_t* a1p = hbout + (size_t)(m0 + row0 + 64) * HH + kc0;
        const ushort_t* w0p = Wf + (size_t)(n0 + row0) * HH + kc0;
        const ushort_t* w1p = Wf + (size_t)(n0 + row0 + 64) * HH + kc0;
        int mq = (wave >> 1) << 6, nq = (wave & 1) << 6;
        int r16 = lane & 15, q = lane >> 4, q8 = q << 3;
        const int lds0 = tid * 8, lds1 = tid * 8 + 2048;
        f32x4 zero4 = {0.f, 0.f, 0.f, 0.f};
        f32x4 acc[4][4];
#pragma unroll
        for (int i = 0; i < 4; ++i)
#pragma unroll
            for (int j = 0; j < 4; ++j) acc[i][j] = zero4;
        for (int k0 = 0; k0 < HH; k0 += 32) {
            int4 va0 = *(const int4*)(a0p + k0);
            int4 va1 = *(const int4*)(a1p + k0);
            int4 vb0 = *(const int4*)(w0p + k0);
            int4 vb1 = *(const int4*)(w1p + k0);
            __syncthreads();
            *(int4*)(As2 + lds0) = va0;
            *(int4*)(As2 + lds1) = va1;
            *(int4*)(Bs2 + lds0) = vb0;
            *(int4*)(Bs2 + lds1) = vb1;
            __syncthreads();
            bf16x8 af[4], bfv[4];
#pragma unroll
            for (int i = 0; i < 4; ++i) af[i] = *(const bf16x8*)(As2 + ((mq + i * 16 + r16) << 5) + q8);
#pragma unroll
            for (int j = 0; j < 4; ++j) bfv[j] = *(const bf16x8*)(Bs2 + ((nq + j * 16 + r16) << 5) + q8);
#pragma unroll
            for (int i = 0; i < 4; ++i)
#pragma unroll
                for (int j = 0; j < 4; ++j) acc[i][j] = MFMA16(af[i], bfv[j], acc[i][j]);
        }
        float bias[4];
#pragma unroll
        for (int j2 = 0; j2 < 4; ++j2) bias[j2] = bfc[n0 + nq + j2 * 16 + r16];
        int nw = wave & 1;
#pragma unroll
        for (int i = 0; i < 4; ++i) {
#pragma unroll
            for (int r = 0; r < 4; ++r) {
                int rloc = mq + i * 16 + q * 4 + r;
                int brow = m0 + rloc;
                int y = targets[brow * TT + t + 1];
                float se = 0.f;
#pragma unroll
                for (int j2 = 0; j2 < 4; ++j2) {
                    float v = acc[i][j2][r] + bias[j2];
                    if (n0 + nq + j2 * 16 + r16 == y) xtv[t * BB + brow] = v;
                    se += expf(v);
                }
#pragma unroll
                for (int d = 1; d < 16; d <<= 1) se += __shfl_xor(se, d, 64);
                if (r16 == 0) ws2[rloc][nw] = se;
            }
        }
        __syncthreads();
        if (tid < 128) {
            float S = ws2[tid][0] + ws2[tid][1];
            atomicAdd(&sum_exp[t * BB + m0 + tid], S);
        }
    }
}

// loss = (1/(T*B*B)) * sum_t msum_t * sum_b (log(S_tb) - xt_tb)
__global__ void finalize(const float* __restrict__ sum_exp, const float* __restrict__ xtv,
                         const int* __restrict__ targets, float* __restrict__ out) {
    __shared__ float msum[TT - 1];
    __shared__ float red[256];
    int tid = threadIdx.x;
    if (tid < TT - 1) {
        int c = 0;
        for (int b = 0; b < BB; ++b) c += (targets[b * TT + tid + 1] >= 1) ? 1 : 0;
        msum[tid] = (float)c;
    }
    __syncthreads();
    float acc = 0.f;
    for (int t = 0; t < TT - 1; ++t)
        acc += (logf(sum_exp[t * BB + tid]) - xtv[t * BB + tid]) * msum[t];
    red[tid] = acc;
    __syncthreads();
    for (int s2 = 128; s2 > 0; s2 >>= 1) {
        if (tid < s2) red[tid] += red[tid + s2];
        __syncthreads();
    }
    if (tid == 0) out[0] = red[0] * (1.f / (256.f * 256.f * 20.f));
}

extern "C" void kernel_launch(void* const* d_in, const int* in_sizes, int n_in,
                              void* d_out, int out_size, void* d_ws, size_t ws_size,
                              hipStream_t stream) {
    const int* inputs = (const int*)d_in[0];
    const int* targets = (const int*)d_in[1];
    const int* lengths = (const int*)d_in[2];
    const float* h0 = (const float*)d_in[3];
    const float* E_enc = (const float*)d_in[4];
    const float* E_dec = (const float*)d_in[5];
    const float* W_ih_e = (const float*)d_in[6];
    const float* W_hh_e = (const float*)d_in[7];
    const float* b_ih_e = (const float*)d_in[8];
    const float* b_hh_e = (const float*)d_in[9];
    const float* W_ih_d = (const float*)d_in[10];
    const float* W_hh_d = (const float*)d_in[11];
    const float* b_ih_d = (const float*)d_in[12];
    const float* b_hh_d = (const float*)d_in[13];
    const float* W_fc = (const float*)d_in[14];
    const float* b_fc = (const float*)d_in[15];

    char* ws = (char*)d_ws;
    size_t off = 0;
    auto alloc = [&](size_t bytes) -> char* {
        char* p = ws + off;
        off += (bytes + 255) & ~(size_t)255;
        return p;
    };
    ushort_t* W_enc_big = (ushort_t*)alloc((size_t)G4 * KE * 2);
    ushort_t* W_dec_pad = (ushort_t*)alloc((size_t)G3 * KE * 2);
    ushort_t* W_hhd_b = (ushort_t*)alloc((size_t)G3 * HH * 2);
    ushort_t* W_fc_b = (ushort_t*)alloc((size_t)VV * HH * 2);
    ushort_t* emb_pad = (ushort_t*)alloc((size_t)SS * BB * 128 * 2);
    ushort_t* A_enc0 = (ushort_t*)alloc((size_t)BB * KE * 2);
    ushort_t* A_enc1 = (ushort_t*)alloc((size_t)BB * KE * 2);
    ushort_t* A_dec = (ushort_t*)alloc((size_t)(TT - 1) * BB * KE * 2);
    ushort_t* gi_dec = (ushort_t*)alloc((size_t)(TT - 1) * BB * G3 * 2);
    float* ctx_f = (float*)alloc((size_t)BB * HH * 4);
    ushort_t* ctx_b = (ushort_t*)alloc((size_t)BB * HH * 2);
    float* h_dec = (float*)alloc((size_t)BB * HH * 4);
    ushort_t* hb0 = (ushort_t*)alloc((size_t)BB * HH * 2);
    ushort_t* hb1 = (ushort_t*)alloc((size_t)BB * HH * 2);
    float* sum_exp = (float*)alloc((size_t)(TT - 1) * BB * 4);
    float* xtv = (float*)alloc((size_t)(TT - 1) * BB * 4);
    int* bars = (int*)alloc(8 * 4);  // [0]=enc cnt, [1]=enc gen, [2]=dec cnt, [3]=dec gen
    ushort_t* hb[2] = {hb0, hb1};

    // ---- prep ----
    prep_w<<<(G4 + G3) * (KE / 8) / 256, 256, 0, stream>>>(W_hh_e, W_ih_e, W_ih_d,
                                                           W_enc_big, W_dec_pad);
    conv_w<<<(G3 * HH + VV * HH) / 8 / 256, 256, 0, stream>>>(W_hh_d, W_fc, W_hhd_b, W_fc_b);
    {
        int nx = SS * BB * 128 + BB * KE + (TT - 1) * BB * 128 + (TT - 1) * BB + 8;
        prep_x<<<(nx + 255) / 256, 256, 0, stream>>>(inputs, targets, h0, E_enc, E_dec,
                                                     emb_pad, A_enc0, A_dec, sum_exp, bars);
    }

    // ---- encoder: one persistent kernel, 64 steps with grid barriers ----
    enc_all<<<dim3(32, 4), 256, 0, stream>>>(A_enc0, A_enc1, W_enc_big, b_ih_e, b_hh_e,
                                             h0, emb_pad, lengths, ctx_f, ctx_b,
                                             &bars[0], &bars[1]);

    // ---- decoder input-side gates: one big GEMM ----
    fill_ctx<<<((TT - 1) * BB * HH) / 256, 256, 0, stream>>>(ctx_f, ctx_b, A_dec, h_dec, hb0);
    gemm128<<<dim3(G3 / 128, (TT - 1) * BB / 128), 256, 0, stream>>>(
        A_dec, W_dec_pad, gi_dec, KE, KE, KE, G3);

    // ---- decoder: 19 fused (recurrence + logits + CE) kernels ----
    for (int t = 0; t < TT - 1; ++t) {
        dec_logits<<<500, 256, 0, stream>>>(hb[t & 1], hb[(t + 1) & 1], W_hhd_b,
                                            gi_dec + (size_t)t * BB * G3,
                                            b_ih_d, b_hh_d, h_dec,
                                            W_fc_b, b_fc, targets, sum_exp, xtv,
                                            &bars[2], &bars[3], t);
    }

    finalize<<<1, 256, 0, stream>>>(sum_exp, xtv, targets, (float*)d_out);
}